// Round 1
// baseline (115.513 us; speedup 1.0000x reference)
//
#include <hip/hip_runtime.h>

// SO(3) exp map (Rodrigues) + translation -> 4x4 matrix, one row per thread.
// Input:  x[B][6] f32  (w = x[:,0:3], t = x[:,3:6])
// Output: out[B][4][4] f32 row-major.
__global__ void __launch_bounds__(256)
so3_to_mat_kernel(const float* __restrict__ x, float* __restrict__ out, int n) {
    const int stride = gridDim.x * blockDim.x;
    for (int i = blockIdx.x * blockDim.x + threadIdx.x; i < n; i += stride) {
        // Row i occupies 24 bytes starting at x + 6*i; 24 is a multiple of 8,
        // so three float2 loads are aligned.
        const float2* xr = reinterpret_cast<const float2*>(x) + 3 * (size_t)i;
        const float2 p0 = xr[0];
        const float2 p1 = xr[1];
        const float2 p2 = xr[2];
        const float wx = p0.x, wy = p0.y, wz = p1.x;
        const float tx = p1.y, ty = p2.x, tz = p2.y;

        const float t2 = wx * wx + wy * wy + wz * wz;
        const bool small = t2 < 1e-8f;

        // Matches reference: theta = sqrt(where(small, 1, t2))
        const float th = sqrtf(small ? 1.0f : t2);
        float s, c;
        sincosf(th, &s, &c);
        const float A  = small ? (1.0f - t2 * (1.0f / 6.0f))  : (s / th);
        const float Bc = small ? (0.5f - t2 * (1.0f / 24.0f)) : ((1.0f - c) / t2);

        // R = I + A*K + B*K^2
        const float xx = wx * wx, yy = wy * wy, zz = wz * wz;
        const float xy = wx * wy, xz = wx * wz, yz = wy * wz;

        const float R00 = 1.0f - Bc * (yy + zz);
        const float R01 = -A * wz + Bc * xy;
        const float R02 =  A * wy + Bc * xz;
        const float R10 =  A * wz + Bc * xy;
        const float R11 = 1.0f - Bc * (xx + zz);
        const float R12 = -A * wx + Bc * yz;
        const float R20 = -A * wy + Bc * xz;
        const float R21 =  A * wx + Bc * yz;
        const float R22 = 1.0f - Bc * (xx + yy);

        float4* o = reinterpret_cast<float4*>(out) + 4 * (size_t)i;
        o[0] = make_float4(R00, R01, R02, tx);
        o[1] = make_float4(R10, R11, R12, ty);
        o[2] = make_float4(R20, R21, R22, tz);
        o[3] = make_float4(0.0f, 0.0f, 0.0f, 1.0f);
    }
}

extern "C" void kernel_launch(void* const* d_in, const int* in_sizes, int n_in,
                              void* d_out, int out_size, void* d_ws, size_t ws_size,
                              hipStream_t stream) {
    const float* x = (const float*)d_in[0];
    float* out = (float*)d_out;
    const int n = in_sizes[0] / 6;  // 4,000,000 rows

    const int block = 256;
    // 2048 blocks * 256 threads = 8192 waves -> 32 waves/CU (max occupancy),
    // grid-stride loop covers the rest (~8 rows/thread).
    int grid = (n + block - 1) / block;
    if (grid > 2048) grid = 2048;

    so3_to_mat_kernel<<<grid, block, 0, stream>>>(x, out, n);
}

// Round 2
// 68.676 us; speedup vs baseline: 1.6820x; 1.6820x over previous
//
#include <hip/hip_runtime.h>

// SO(3) exp map (Rodrigues) + translation -> 4x4 matrix.
// Input:  x[B][6] f32  (w = x[:,0:3], t = x[:,3:6])
// Output: out[B][4][4] f32 row-major.
//
// One row per thread, but stores are staged through LDS so that global
// writes are fully coalesced (lane-consecutive float4), instead of each
// thread writing its own 64B row at stride 64 (4x transaction blowup).

#define TPB 256
// Padded row length (in float4 units) for the LDS transpose buffer.
// P4 % 8 == 2 makes both the write pattern (lane-linear in r) and the
// read pattern (A = (t&3)*P4 + (t>>2)) exactly 2-lanes-per-bank => free.
#define P4 258

__global__ void __launch_bounds__(TPB)
so3_to_mat_kernel(const float* __restrict__ x, float* __restrict__ out, int n) {
    __shared__ float4 buf[4 * P4];  // buf[s*P4 + r] = float4 #s of tile-row r
    const int t = threadIdx.x;
    const int ntiles = (n + TPB - 1) / TPB;

    for (int tile = blockIdx.x; tile < ntiles; tile += gridDim.x) {
        const int base = tile * TPB;
        const int row = base + t;

        if (row < n) {
            // Row occupies 24 B at x + 6*row; 8-B aligned -> three float2 loads.
            const float2* xr = reinterpret_cast<const float2*>(x) + 3 * (size_t)row;
            const float2 p0 = xr[0];
            const float2 p1 = xr[1];
            const float2 p2 = xr[2];
            const float wx = p0.x, wy = p0.y, wz = p1.x;
            const float tx = p1.y, ty = p2.x, tz = p2.y;

            const float t2 = wx * wx + wy * wy + wz * wz;
            const bool small = t2 < 1e-8f;

            const float th = sqrtf(small ? 1.0f : t2);
            float s, c;
            sincosf(th, &s, &c);
            const float A  = small ? (1.0f - t2 * (1.0f / 6.0f))  : (s / th);
            const float Bc = small ? (0.5f - t2 * (1.0f / 24.0f)) : ((1.0f - c) / t2);

            const float xx = wx * wx, yy = wy * wy, zz = wz * wz;
            const float xy = wx * wy, xz = wx * wz, yz = wy * wz;

            buf[0 * P4 + t] = make_float4(1.0f - Bc * (yy + zz),
                                          -A * wz + Bc * xy,
                                           A * wy + Bc * xz,
                                          tx);
            buf[1 * P4 + t] = make_float4( A * wz + Bc * xy,
                                          1.0f - Bc * (xx + zz),
                                          -A * wx + Bc * yz,
                                          ty);
            buf[2 * P4 + t] = make_float4(-A * wy + Bc * xz,
                                           A * wx + Bc * yz,
                                          1.0f - Bc * (xx + yy),
                                          tz);
            buf[3 * P4 + t] = make_float4(0.0f, 0.0f, 0.0f, 1.0f);
        }
        __syncthreads();

        // Coalesced write-out: tile is 256 rows * 4 float4 = 1024 float4.
        // Thread t writes global float4 indices t, t+256, t+512, t+768.
        const int nrow = min(TPB, n - base);
        float4* ob = reinterpret_cast<float4*>(out) + 4 * (size_t)base;
        #pragma unroll
        for (int m = 0; m < 4; ++m) {
            const int g = t + TPB * m;
            if (g < 4 * nrow) {
                const int r = g >> 2;
                const int s4 = g & 3;
                ob[g] = buf[s4 * P4 + r];
            }
        }
        __syncthreads();  // protect LDS before next tile's writes
    }
}

extern "C" void kernel_launch(void* const* d_in, const int* in_sizes, int n_in,
                              void* d_out, int out_size, void* d_ws, size_t ws_size,
                              hipStream_t stream) {
    const float* x = (const float*)d_in[0];
    float* out = (float*)d_out;
    const int n = in_sizes[0] / 6;  // 4,000,000 rows

    const int ntiles = (n + TPB - 1) / TPB;
    int grid = ntiles < 2048 ? ntiles : 2048;

    so3_to_mat_kernel<<<grid, TPB, 0, stream>>>(x, out, n);
}